// Round 7
// baseline (210.446 us; speedup 1.0000x reference)
//
#include <hip/hip_runtime.h>
#include <stdint.h>

// Problem constants: B=8, S=2048, D=256, DK=DV=128
typedef float    f32x4 __attribute__((ext_vector_type(4)));
typedef _Float16 f16x8 __attribute__((ext_vector_type(8)));
typedef _Float16 f16x4 __attribute__((ext_vector_type(4)));
typedef unsigned int u32x4 __attribute__((ext_vector_type(4)));

#define SPLIT 4
#define NTILES 8   // 32 / SPLIT

__device__ __forceinline__ f32x4 mfma16(f16x8 a, f16x8 b, f32x4 c) {
    return __builtin_amdgcn_mfma_f32_16x16x32_f16(a, b, c, 0, 0, 0);
}
__device__ __forceinline__ f32x4 mfma16k16(f16x4 a, f16x4 b, f32x4 c) {
    return __builtin_amdgcn_mfma_f32_16x16x16f16(a, b, c, 0, 0, 0);
}

// ---------------------------------------------------------------------------
// Kernel 0: transpose+convert W[256][128] f32 -> Wt[w][n][k]=[3][128][256] f16
// ---------------------------------------------------------------------------
__global__ __launch_bounds__(256) void prep_weights(
    const float* __restrict__ Wq, const float* __restrict__ Wk,
    const float* __restrict__ Wv, _Float16* __restrict__ wt) {
    __shared__ float Ls[64 * 65];
    const int bx = blockIdx.x;
    const int w  = bx >> 3, t = bx & 7;
    const int k0 = (t >> 1) * 64, n0 = (t & 1) * 64;
    const float* W = (w == 0) ? Wq : (w == 1) ? Wk : Wv;
    const int tid = threadIdx.x;
    #pragma unroll
    for (int i = 0; i < 16; i++) {
        int idx = i * 256 + tid;
        int r = idx >> 6, c = idx & 63;
        Ls[r * 65 + c] = W[(k0 + r) * 128 + n0 + c];
    }
    __syncthreads();
    #pragma unroll
    for (int i = 0; i < 16; i++) {
        int idx = i * 256 + tid;
        int r2 = idx >> 6, c2 = idx & 63;
        wt[w * 32768 + (n0 + r2) * 256 + k0 + c2] = (_Float16)Ls[c2 * 65 + r2];
    }
}

// ---------------------------------------------------------------------------
// Kernel 1: projections, barrier-free / LDS-free (weights L1/L2-resident).
// ---------------------------------------------------------------------------
__global__ __launch_bounds__(256) void proj_kernel(
    const float* __restrict__ xq, const float* __restrict__ xk,
    const float* __restrict__ xv, const _Float16* __restrict__ wt,
    const float* __restrict__ bq, const float* __restrict__ bk,
    const float* __restrict__ bv,
    _Float16* __restrict__ qo, _Float16* __restrict__ ko,
    _Float16* __restrict__ vtmp)
{
    const int mode = blockIdx.y;
    const float*    X    = mode == 0 ? xq : mode == 1 ? xk : xv;
    const float*    bias = mode == 0 ? bq : mode == 1 ? bk : bv;
    const _Float16* W    = wt + mode * 32768;
    _Float16*       Y    = mode == 0 ? qo : mode == 1 ? ko : vtmp;

    const int tid  = threadIdx.x;
    const int wave = tid >> 6, lane = tid & 63;
    const int ln   = lane & 15, qd = lane >> 4;
    const int row0 = blockIdx.x * 64 + wave * 16;

    const float*    xrow = X + (size_t)(row0 + ln) * 256 + qd * 8;
    const _Float16* wb   = W + ln * 256 + qd * 8;

    f32x4 acc[8];
    #pragma unroll
    for (int i = 0; i < 8; i++) acc[i] = (f32x4){0.f, 0.f, 0.f, 0.f};

    #pragma unroll
    for (int kk = 0; kk < 8; kk++) {
        f32x4 a0 = *(const f32x4*)(xrow + kk * 32);
        f32x4 a1 = *(const f32x4*)(xrow + kk * 32 + 4);
        f16x8 af;
        af[0] = (_Float16)a0[0]; af[1] = (_Float16)a0[1];
        af[2] = (_Float16)a0[2]; af[3] = (_Float16)a0[3];
        af[4] = (_Float16)a1[0]; af[5] = (_Float16)a1[1];
        af[6] = (_Float16)a1[2]; af[7] = (_Float16)a1[3];
        #pragma unroll
        for (int nt = 0; nt < 8; nt++) {
            f16x8 bf = *(const f16x8*)(wb + nt * 4096 + kk * 32);
            acc[nt] = mfma16(af, bf, acc[nt]);
        }
    }

    const float SC = 0.08838834764831845f * 1.4426950408889634f;
    #pragma unroll
    for (int nt = 0; nt < 8; nt++) {
        int col = nt * 16 + ln;
        float bb = bias[col];
        #pragma unroll
        for (int r = 0; r < 4; r++) {
            int orow = row0 + qd * 4 + r;
            float val = acc[nt][r] + bb;
            if (mode == 0) val *= SC;
            Y[(size_t)orow * 128 + col] = (_Float16)val;
        }
    }
}

// ---------------------------------------------------------------------------
// Kernel 1b: transpose V: vtmp[b][s][128] -> vt[b][128][2048].
// ---------------------------------------------------------------------------
__global__ __launch_bounds__(256) void transpose_v(
    const _Float16* __restrict__ vtmp, _Float16* __restrict__ vt)
{
    __shared__ __align__(16) _Float16 Ls[64 * 72];
    const int b  = blockIdx.z;
    const int s0 = blockIdx.x * 64;
    const int d0 = blockIdx.y * 64;
    const int tid = threadIdx.x;
    #pragma unroll
    for (int i = 0; i < 2; i++) {
        int idx = i * 256 + tid;
        int r = idx >> 3, c = (idx & 7) * 8;
        *(f16x8*)&Ls[r * 72 + c] =
            *(const f16x8*)(vtmp + (size_t)(b * 2048 + s0 + r) * 128 + d0 + c);
    }
    __syncthreads();
    #pragma unroll
    for (int i = 0; i < 2; i++) {
        int idx = i * 256 + tid;
        int dr = idx >> 3, sc8 = (idx & 7) * 8;
        f16x8 o;
        #pragma unroll
        for (int j = 0; j < 8; j++) o[j] = Ls[(sc8 + j) * 72 + dr];
        *(f16x8*)(vt + (size_t)(b * 128 + d0 + dr) * 2048 + s0 + sc8) = o;
    }
}

// ---------------------------------------------------------------------------
// Kernel 2: flash attention, transposed-score (S^T = K Q^T), 256-thr blocks.
// 4 waves x 64 q-rows; grid 1024 = 4 blocks/CU (finer barrier groups than
// R6's 2x8-wave). Register prefetch of tile t+1 K/V (32 VGPRs) issued after
// the staging barrier -> global-load latency overlaps compute of tile t.
// launch_bounds(256,4): 128-reg budget, no spill (R5 lesson). XCD-pinned
// decode keeps each (b,z) 262 KB K/V stream on one XCD's L2.
// ---------------------------------------------------------------------------
__global__ __launch_bounds__(256, 4) void attn_kernel(
    const _Float16* __restrict__ qp, const _Float16* __restrict__ kp,
    const _Float16* __restrict__ vtp, _Float16* __restrict__ opart,
    float2* __restrict__ ml)
{
    // decode: xcd fastest (round-robin pin), then q0 (32 tiles), then group
    const int bid = blockIdx.x;
    const int gx  = bid & 7;
    const int q0i = (bid >> 3) & 31;
    const int gg  = bid >> 8;            // 0..3
    const int g   = gg * 8 + gx;         // 0..31 = b*SPLIT+z
    const int b   = g >> 2;
    const int z   = g & 3;
    const int q0  = q0i * 64;

    const int tid  = threadIdx.x;
    const int wave = tid >> 6, lane = tid & 63;
    const int ln   = lane & 15, qd = lane >> 4;

    // unified LDS: Ks = [64][136] (8704 f16), Vs = [128][72] (9216 f16)
    __shared__ __align__(16) _Float16 smem[17920];
    _Float16* Ks = smem;
    _Float16* Vs = smem + 8704;

    const _Float16* qrow =
        qp + (size_t)(b * 2048 + q0 + wave * 16 + ln) * 128 + qd * 8;
    f16x8 qf[4];
    #pragma unroll
    for (int c = 0; c < 4; c++) qf[c] = *(const f16x8*)(qrow + c * 32);

    f32x4 o[8];                       // O^T accum: dv = dt*16+qd*4+r, q = ln
    #pragma unroll
    for (int i = 0; i < 8; i++) o[i] = (f32x4){0.f, 0.f, 0.f, 0.f};
    float m_run = -1e30f, l_run = 0.f;

    const _Float16* kbase = kp + (size_t)b * 2048 * 128;
    const _Float16* vbase = vtp + (size_t)b * 128 * 2048;

    const int kt0 = z * NTILES;
    u32x4 kpre[4], vpre[4];
    {   // prefetch first tile into registers
        const _Float16* ks = kbase + (size_t)kt0 * 64 * 128;
        const _Float16* vs = vbase + kt0 * 64;
        #pragma unroll
        for (int j = 0; j < 4; j++) {
            int i = j * 256 + tid;
            kpre[j] = *(const u32x4*)(ks + (i >> 4) * 128 + (i & 15) * 8);
            vpre[j] = *(const u32x4*)(vs + (size_t)(i >> 3) * 2048 + (i & 7) * 8);
        }
    }

    for (int kt = kt0; kt < kt0 + NTILES; kt++) {
        __syncthreads();              // all waves done reading prev LDS tile
        #pragma unroll
        for (int j = 0; j < 4; j++) { // stage prefetched regs -> LDS
            int i = j * 256 + tid;
            *(u32x4*)&Ks[(i >> 4) * 136 + (i & 15) * 8] = kpre[j];
            *(u32x4*)&Vs[(i >> 3) * 72 + (i & 7) * 8]   = vpre[j];
        }
        __syncthreads();
        if (kt + 1 < kt0 + NTILES) {  // prefetch next tile (overlaps compute)
            const _Float16* ks = kbase + (size_t)(kt + 1) * 64 * 128;
            const _Float16* vs = vbase + (kt + 1) * 64;
            #pragma unroll
            for (int j = 0; j < 4; j++) {
                int i = j * 256 + tid;
                kpre[j] = *(const u32x4*)(ks + (i >> 4) * 128 + (i & 15) * 8);
                vpre[j] = *(const u32x4*)(vs + (size_t)(i >> 3) * 2048 + (i & 7) * 8);
            }
        }

        // S^T = K Q^T : lane holds kv = st*16+qd*4+r, q = ln
        f32x4 sc[4];
        #pragma unroll
        for (int st = 0; st < 4; st++) {
            sc[st] = (f32x4){0.f, 0.f, 0.f, 0.f};
            int base = (st * 16 + ln) * 136 + qd * 8;
            #pragma unroll
            for (int c = 0; c < 4; c++) {
                f16x8 kf = *(const f16x8*)&Ks[base + c * 32];
                sc[st] = mfma16(kf, qf[c], sc[st]);   // A=K, B=Q -> S^T
            }
        }

        // online softmax, per-lane scalar state (q = ln)
        float t = sc[0][0];
        #pragma unroll
        for (int st = 0; st < 4; st++)
            #pragma unroll
            for (int r = 0; r < 4; r++) t = fmaxf(t, sc[st][r]);
        t = fmaxf(t, __shfl_xor(t, 16));
        t = fmaxf(t, __shfl_xor(t, 32));
        const float mnew  = fmaxf(m_run, t);
        const float alpha = exp2f(m_run - mnew);

        f16x4 ph[4];
        float ssum = 0.f;
        #pragma unroll
        for (int st = 0; st < 4; st++) {
            #pragma unroll
            for (int r = 0; r < 4; r++) {
                float p = exp2f(sc[st][r] - mnew);
                ssum += p;
                ph[st][r] = (_Float16)p;
            }
        }
        ssum += __shfl_xor(ssum, 16);
        ssum += __shfl_xor(ssum, 32);
        l_run = l_run * alpha + ssum;
        m_run = mnew;

        // wave-uniform skip: rescale only if any lane's max moved
        if (__any(alpha != 1.0f)) {
            #pragma unroll
            for (int dt = 0; dt < 8; dt++)
                #pragma unroll
                for (int r = 0; r < 4; r++) o[dt][r] *= alpha;
        }

        // O^T += V^T * P^T : P^T C-layout == B-frag of 16x16x16 (k=qd*4+r)
        #pragma unroll
        for (int st = 0; st < 4; st++) {
            #pragma unroll
            for (int dt = 0; dt < 8; dt++) {
                f16x4 vf = *(const f16x4*)&Vs[(dt * 16 + ln) * 72 + st * 16 + qd * 4];
                o[dt] = mfma16k16(vf, ph[st], o[dt]);
            }
        }
    }

    // ---- epilogue: O^T -> LDS (wave-private) -> coalesced global stores ----
    __syncthreads();                       // all waves done reading Ks/Vs
    _Float16* pw = smem + wave * 2176;     // 16 rows x 136 f16
    #pragma unroll
    for (int dt = 0; dt < 8; dt++) {
        f16x4 h;
        #pragma unroll
        for (int r = 0; r < 4; r++) h[r] = (_Float16)o[dt][r];
        *(f16x4*)&pw[ln * 136 + dt * 16 + qd * 4] = h;   // row = q (ln)
    }
    const size_t prow = (size_t)(z * 8 + b) * 2048 + q0 + wave * 16;
    __builtin_amdgcn_s_waitcnt(0);  // lgkmcnt(0): wave-private LDS round-trip
    #pragma unroll
    for (int i = 0; i < 4; i++) {
        int row = i * 4 + qd;
        f16x8 vrow = *(const f16x8*)&pw[row * 136 + ln * 8];
        *(f16x8*)(opart + (prow + row) * 128 + ln * 8) = vrow;  // 16B/lane
    }
    if (qd == 0) {
        float2 v; v.x = m_run; v.y = l_run;
        ml[prow + ln] = v;
    }
}

// ---------------------------------------------------------------------------
// Kernel 3: merge SPLIT partials. Block = 16 rows x 128 cols, grid 1024.
// ---------------------------------------------------------------------------
__global__ __launch_bounds__(256) void merge_kernel(
    const _Float16* __restrict__ opart, const float2* __restrict__ ml,
    float* __restrict__ out)
{
    const int t = threadIdx.x;
    const int r = t >> 4, cg = t & 15;
    const size_t row = (size_t)blockIdx.x * 16 + r;   // 0..16383 = b*2048+s

    float M = -1e30f;
    #pragma unroll
    for (int zi = 0; zi < SPLIT; zi++)
        M = fmaxf(M, ml[(size_t)zi * 16384 + row].x);
    float L = 0.f;
    float acc[8] = {0.f, 0.f, 0.f, 0.f, 0.f, 0.f, 0.f, 0.f};
    #pragma unroll
    for (int zi = 0; zi < SPLIT; zi++) {
        float2 p = ml[(size_t)zi * 16384 + row];
        float w = exp2f(p.x - M);
        L += w * p.y;
        f16x8 v = *(const f16x8*)&opart[((size_t)zi * 16384 + row) * 128 + cg * 8];
        #pragma unroll
        for (int j = 0; j < 8; j++) acc[j] += w * (float)v[j];
    }
    const float inv = 1.0f / L;
    float* op = out + row * 128 + cg * 8;
    f32x4 lo = (f32x4){acc[0] * inv, acc[1] * inv, acc[2] * inv, acc[3] * inv};
    f32x4 hi = (f32x4){acc[4] * inv, acc[5] * inv, acc[6] * inv, acc[7] * inv};
    *(f32x4*)op = lo;
    *(f32x4*)(op + 4) = hi;
}

// ---------------------------------------------------------------------------
extern "C" void kernel_launch(void* const* d_in, const int* in_sizes, int n_in,
                              void* d_out, int out_size, void* d_ws, size_t ws_size,
                              hipStream_t stream) {
    const float* xq = (const float*)d_in[0];
    const float* xk = (const float*)d_in[1];
    const float* xv = (const float*)d_in[2];
    const float* Wq = (const float*)d_in[3];
    const float* bq = (const float*)d_in[4];
    const float* Wk = (const float*)d_in[5];
    const float* bk = (const float*)d_in[6];
    const float* Wv = (const float*)d_in[7];
    const float* bv = (const float*)d_in[8];
    float* out = (float*)d_out;

    // ws layout: wt 192K | qo 4M | ko 4M | vt 4M | ml 1M | opart SPLIT*4M
    char* ws = (char*)d_ws;
    _Float16* wt    = (_Float16*)ws;
    _Float16* qo    = (_Float16*)(ws + 196608);
    _Float16* ko    = (_Float16*)(ws + 196608 + 4194304);
    _Float16* vt    = (_Float16*)(ws + 196608 + 2 * 4194304);
    float2*   ml    = (float2*)  (ws + 196608 + 3 * 4194304);
    _Float16* opart = (_Float16*)(ws + 196608 + 3 * 4194304 + 1048576);
    _Float16* vtmp  = opart;   // alias, lifetime disjoint

    hipLaunchKernelGGL(prep_weights, dim3(24), dim3(256), 0, stream,
                       Wq, Wk, Wv, wt);
    hipLaunchKernelGGL(proj_kernel, dim3(256, 3), dim3(256), 0, stream,
                       xq, xk, xv, wt, bq, bk, bv, qo, ko, vtmp);
    hipLaunchKernelGGL(transpose_v, dim3(32, 2, 8), dim3(256), 0, stream,
                       vtmp, vt);
    hipLaunchKernelGGL(attn_kernel, dim3(32 * 8 * SPLIT), dim3(256), 0, stream,
                       qo, ko, vt, opart, ml);
    hipLaunchKernelGGL(merge_kernel, dim3(1024), dim3(256), 0, stream,
                       opart, ml, out);
}

// Round 9
// 163.960 us; speedup vs baseline: 1.2835x; 1.2835x over previous
//
#include <hip/hip_runtime.h>
#include <stdint.h>

// Problem constants: B=8, S=2048, D=256, DK=DV=128
typedef float    f32x4 __attribute__((ext_vector_type(4)));
typedef _Float16 f16x8 __attribute__((ext_vector_type(8)));
typedef _Float16 f16x4 __attribute__((ext_vector_type(4)));
typedef unsigned int u32x4 __attribute__((ext_vector_type(4)));

#define SPLIT 4
#define NTILES 8   // 32 / SPLIT

__device__ __forceinline__ f32x4 mfma16(f16x8 a, f16x8 b, f32x4 c) {
    return __builtin_amdgcn_mfma_f32_16x16x32_f16(a, b, c, 0, 0, 0);
}
__device__ __forceinline__ f32x4 mfma16k16(f16x4 a, f16x4 b, f32x4 c) {
    return __builtin_amdgcn_mfma_f32_16x16x16f16(a, b, c, 0, 0, 0);
}
// async global->LDS DMA, 16 B/lane; LDS dest = base + lane*16 (wave-uniform base)
__device__ __forceinline__ void gll16(const _Float16* g, _Float16* l) {
    __builtin_amdgcn_global_load_lds(
        (const __attribute__((address_space(1))) void*)g,
        (__attribute__((address_space(3))) void*)l, 16, 0, 0);
}

// ---------------------------------------------------------------------------
// Kernel 0: transpose+convert W[256][128] f32 -> Wt[w][n][k]=[3][128][256] f16
// ---------------------------------------------------------------------------
__global__ __launch_bounds__(256) void prep_weights(
    const float* __restrict__ Wq, const float* __restrict__ Wk,
    const float* __restrict__ Wv, _Float16* __restrict__ wt) {
    __shared__ float Ls[64 * 65];
    const int bx = blockIdx.x;
    const int w  = bx >> 3, t = bx & 7;
    const int k0 = (t >> 1) * 64, n0 = (t & 1) * 64;
    const float* W = (w == 0) ? Wq : (w == 1) ? Wk : Wv;
    const int tid = threadIdx.x;
    #pragma unroll
    for (int i = 0; i < 16; i++) {
        int idx = i * 256 + tid;
        int r = idx >> 6, c = idx & 63;
        Ls[r * 65 + c] = W[(k0 + r) * 128 + n0 + c];
    }
    __syncthreads();
    #pragma unroll
    for (int i = 0; i < 16; i++) {
        int idx = i * 256 + tid;
        int r2 = idx >> 6, c2 = idx & 63;
        wt[w * 32768 + (n0 + r2) * 256 + k0 + c2] = (_Float16)Ls[c2 * 65 + r2];
    }
}

// ---------------------------------------------------------------------------
// Kernel 1: projections, barrier-free / LDS-free (weights L1/L2-resident).
// ---------------------------------------------------------------------------
__global__ __launch_bounds__(256) void proj_kernel(
    const float* __restrict__ xq, const float* __restrict__ xk,
    const float* __restrict__ xv, const _Float16* __restrict__ wt,
    const float* __restrict__ bq, const float* __restrict__ bk,
    const float* __restrict__ bv,
    _Float16* __restrict__ qo, _Float16* __restrict__ ko,
    _Float16* __restrict__ vtmp)
{
    const int mode = blockIdx.y;
    const float*    X    = mode == 0 ? xq : mode == 1 ? xk : xv;
    const float*    bias = mode == 0 ? bq : mode == 1 ? bk : bv;
    const _Float16* W    = wt + mode * 32768;
    _Float16*       Y    = mode == 0 ? qo : mode == 1 ? ko : vtmp;

    const int tid  = threadIdx.x;
    const int wave = tid >> 6, lane = tid & 63;
    const int ln   = lane & 15, qd = lane >> 4;
    const int row0 = blockIdx.x * 64 + wave * 16;

    const float*    xrow = X + (size_t)(row0 + ln) * 256 + qd * 8;
    const _Float16* wb   = W + ln * 256 + qd * 8;

    f32x4 acc[8];
    #pragma unroll
    for (int i = 0; i < 8; i++) acc[i] = (f32x4){0.f, 0.f, 0.f, 0.f};

    #pragma unroll
    for (int kk = 0; kk < 8; kk++) {
        f32x4 a0 = *(const f32x4*)(xrow + kk * 32);
        f32x4 a1 = *(const f32x4*)(xrow + kk * 32 + 4);
        f16x8 af;
        af[0] = (_Float16)a0[0]; af[1] = (_Float16)a0[1];
        af[2] = (_Float16)a0[2]; af[3] = (_Float16)a0[3];
        af[4] = (_Float16)a1[0]; af[5] = (_Float16)a1[1];
        af[6] = (_Float16)a1[2]; af[7] = (_Float16)a1[3];
        #pragma unroll
        for (int nt = 0; nt < 8; nt++) {
            f16x8 bf = *(const f16x8*)(wb + nt * 4096 + kk * 32);
            acc[nt] = mfma16(af, bf, acc[nt]);
        }
    }

    const float SC = 0.08838834764831845f * 1.4426950408889634f;
    #pragma unroll
    for (int nt = 0; nt < 8; nt++) {
        int col = nt * 16 + ln;
        float bb = bias[col];
        #pragma unroll
        for (int r = 0; r < 4; r++) {
            int orow = row0 + qd * 4 + r;
            float val = acc[nt][r] + bb;
            if (mode == 0) val *= SC;
            Y[(size_t)orow * 128 + col] = (_Float16)val;
        }
    }
}

// ---------------------------------------------------------------------------
// Kernel 1b: transpose V: vtmp[b][s][128] -> vt[b][128][2048].
// ---------------------------------------------------------------------------
__global__ __launch_bounds__(256) void transpose_v(
    const _Float16* __restrict__ vtmp, _Float16* __restrict__ vt)
{
    __shared__ __align__(16) _Float16 Ls[64 * 72];
    const int b  = blockIdx.z;
    const int s0 = blockIdx.x * 64;
    const int d0 = blockIdx.y * 64;
    const int tid = threadIdx.x;
    #pragma unroll
    for (int i = 0; i < 2; i++) {
        int idx = i * 256 + tid;
        int r = idx >> 3, c = (idx & 7) * 8;
        *(f16x8*)&Ls[r * 72 + c] =
            *(const f16x8*)(vtmp + (size_t)(b * 2048 + s0 + r) * 128 + d0 + c);
    }
    __syncthreads();
    #pragma unroll
    for (int i = 0; i < 2; i++) {
        int idx = i * 256 + tid;
        int dr = idx >> 3, sc8 = (idx & 7) * 8;
        f16x8 o;
        #pragma unroll
        for (int j = 0; j < 8; j++) o[j] = Ls[(sc8 + j) * 72 + dr];
        *(f16x8*)(vt + (size_t)(b * 128 + d0 + dr) * 2048 + s0 + sc8) = o;
    }
}

// ---------------------------------------------------------------------------
// Kernel 2: flash attention, S^T = K Q^T formulation (R6 base, 42.4 us),
// with zero-register async staging: global_load_lds (16B) into double-
// buffered LDS (2xK + 2xV = 64 KB), selected by COMPUTED OFFSET (R8's
// pointer-array init hit the addrspacecast static-initializer error).
// One barrier per K-tile; DMA for tile t+1 issued right after the barrier
// overlaps compute of tile t. gll needs unpadded LDS (dest=base+lane*16),
// so the SOURCE granule is XOR-swizzled per lane -> uniform bank spread.
// launch_bounds(512,4): 128-reg total budget, no spill, 2 blocks/CU.
// ---------------------------------------------------------------------------
__global__ __launch_bounds__(512, 4) void attn_kernel(
    const _Float16* __restrict__ qp, const _Float16* __restrict__ kp,
    const _Float16* __restrict__ vtp, _Float16* __restrict__ opart,
    float2* __restrict__ ml)
{
    // decode: xcd fastest (round-robin pin), then q0, then group-high
    const int bid = blockIdx.x;
    const int gx  = bid & 7;
    const int q0i = (bid >> 3) & 15;
    const int gg  = bid >> 7;            // 0..3
    const int g   = gg * 8 + gx;         // 0..31 = b*SPLIT+z
    const int b   = g >> 2;
    const int z   = g & 3;
    const int q0  = q0i * 128;

    const int tid  = threadIdx.x;
    const int wave = tid >> 6, lane = tid & 63;
    const int ln   = lane & 15, qd = lane >> 4;

    // 64 KB: K buffers [64][128] f16 x2 at 0/8192, V [128][64] f16 x2 at 16384/24576
    __shared__ __align__(16) _Float16 smem[32768];

    const _Float16* qrow =
        qp + (size_t)(b * 2048 + q0 + wave * 16 + ln) * 128 + qd * 8;
    f16x8 qf[4];
    #pragma unroll
    for (int c = 0; c < 4; c++) qf[c] = *(const f16x8*)(qrow + c * 32);

    f32x4 o[8];                       // O^T accum: dv = dt*16+qd*4+r, q = ln
    #pragma unroll
    for (int i = 0; i < 8; i++) o[i] = (f32x4){0.f, 0.f, 0.f, 0.f};
    float m_run = -1e30f, l_run = 0.f;

    const _Float16* kbase = kp + (size_t)b * 2048 * 128;
    const _Float16* vbase = vtp + (size_t)b * 128 * 2048;
    const int kt0 = z * NTILES;

    // ---- async stage of one K/V tile (4 gll per wave, swizzled source) ----
    auto stage = [&](int kt, int buf) {
        const _Float16* ks = kbase + (size_t)kt * 64 * 128;
        const _Float16* vs = vbase + kt * 64;
        _Float16* kdst0 = smem + buf * 8192;
        _Float16* vdst0 = smem + 16384 + buf * 8192;
        #pragma unroll
        for (int j = 0; j < 2; j++) {
            int p  = wave * 128 + j * 64 + lane;          // K granule 0..1023
            int r  = p >> 4, cp = p & 15;
            int cl = cp ^ (r & 15);
            gll16(ks + r * 128 + cl * 8, kdst0 + (wave * 128 + j * 64) * 8);
            int dv = p >> 3, cq = p & 7;                  // V granule 0..1023
            int c2 = cq ^ (dv & 7);
            gll16(vs + (size_t)dv * 2048 + c2 * 8, vdst0 + (wave * 128 + j * 64) * 8);
        }
    };

    stage(kt0, 0);

    for (int it = 0; it < NTILES; it++) {
        __syncthreads();   // drains vmcnt: tile `it` landed; other buf free
        if (it + 1 < NTILES) stage(kt0 + it + 1, (it + 1) & 1);
        const _Float16* kb = smem + (it & 1) * 8192;
        const _Float16* vb = smem + 16384 + (it & 1) * 8192;

        // S^T = K Q^T : lane holds kv = st*16+qd*4+r, q = ln
        // swizzled read: row = st*16+ln (row&15==ln), granule (c*4+qd)^ln
        f32x4 sc[4];
        #pragma unroll
        for (int st = 0; st < 4; st++) {
            sc[st] = (f32x4){0.f, 0.f, 0.f, 0.f};
            int base = (st * 16 + ln) * 128;
            #pragma unroll
            for (int c = 0; c < 4; c++) {
                f16x8 kf = *(const f16x8*)&kb[base + ((c * 4 + qd) ^ ln) * 8];
                sc[st] = mfma16(kf, qf[c], sc[st]);   // A=K, B=Q -> S^T
            }
        }

        // online softmax, per-lane scalar state (q = ln)
        float t = sc[0][0];
        #pragma unroll
        for (int st = 0; st < 4; st++)
            #pragma unroll
            for (int r = 0; r < 4; r++) t = fmaxf(t, sc[st][r]);
        t = fmaxf(t, __shfl_xor(t, 16));
        t = fmaxf(t, __shfl_xor(t, 32));
        const float mnew  = fmaxf(m_run, t);
        const float alpha = exp2f(m_run - mnew);

        f16x4 ph[4];
        float ssum = 0.f;
        #pragma unroll
        for (int st = 0; st < 4; st++) {
            #pragma unroll
            for (int r = 0; r < 4; r++) {
                float p = exp2f(sc[st][r] - mnew);
                ssum += p;
                ph[st][r] = (_Float16)p;
            }
        }
        ssum += __shfl_xor(ssum, 16);
        ssum += __shfl_xor(ssum, 32);
        l_run = l_run * alpha + ssum;
        m_run = mnew;

        #pragma unroll
        for (int dt = 0; dt < 8; dt++)
            #pragma unroll
            for (int r = 0; r < 4; r++) o[dt][r] *= alpha;

        // O^T += V^T * P^T : P^T C-layout == B-frag of 16x16x16 (k=qd*4+r)
        // swizzled read: row dv = dt*16+ln, granule (st*2+(qd>>1))^(ln&7),
        // half-granule select (qd&1)*4
        #pragma unroll
        for (int st = 0; st < 4; st++) {
            #pragma unroll
            for (int dt = 0; dt < 8; dt++) {
                f16x4 vf = *(const f16x4*)&vb[(dt * 16 + ln) * 64 +
                           ((st * 2 + (qd >> 1)) ^ (ln & 7)) * 8 + (qd & 1) * 4];
                o[dt] = mfma16k16(vf, ph[st], o[dt]);
            }
        }
    }

    // ---- epilogue: O^T -> LDS (wave-private) -> coalesced global stores ----
    __syncthreads();                       // all waves done with K/V buffers
    _Float16* pw = smem + wave * 2176;     // 16 rows x 136 f16
    #pragma unroll
    for (int dt = 0; dt < 8; dt++) {
        f16x4 h;
        #pragma unroll
        for (int r = 0; r < 4; r++) h[r] = (_Float16)o[dt][r];
        *(f16x4*)&pw[ln * 136 + dt * 16 + qd * 4] = h;   // row = q (ln)
    }
    const size_t prow = (size_t)(z * 8 + b) * 2048 + q0 + wave * 16;
    __builtin_amdgcn_s_waitcnt(0);  // wave-private LDS round-trip
    #pragma unroll
    for (int i = 0; i < 4; i++) {
        int row = i * 4 + qd;
        f16x8 vrow = *(const f16x8*)&pw[row * 136 + ln * 8];
        *(f16x8*)(opart + (prow + row) * 128 + ln * 8) = vrow;  // 16B/lane
    }
    if (qd == 0) {
        float2 v; v.x = m_run; v.y = l_run;
        ml[prow + ln] = v;
    }
}

// ---------------------------------------------------------------------------
// Kernel 3: merge SPLIT partials. Block = 16 rows x 128 cols, grid 1024.
// ---------------------------------------------------------------------------
__global__ __launch_bounds__(256) void merge_kernel(
    const _Float16* __restrict__ opart, const float2* __restrict__ ml,
    float* __restrict__ out)
{
    const int t = threadIdx.x;
    const int r = t >> 4, cg = t & 15;
    const size_t row = (size_t)blockIdx.x * 16 + r;   // 0..16383 = b*2048+s

    float M = -1e30f;
    #pragma unroll
    for (int zi = 0; zi < SPLIT; zi++)
        M = fmaxf(M, ml[(size_t)zi * 16384 + row].x);
    float L = 0.f;
    float acc[8] = {0.f, 0.f, 0.f, 0.f, 0.f, 0.f, 0.f, 0.f};
    #pragma unroll
    for (int zi = 0; zi < SPLIT; zi++) {
        float2 p = ml[(size_t)zi * 16384 + row];
        float w = exp2f(p.x - M);
        L += w * p.y;
        f16x8 v = *(const f16x8*)&opart[((size_t)zi * 16384 + row) * 128 + cg * 8];
        #pragma unroll
        for (int j = 0; j < 8; j++) acc[j] += w * (float)v[j];
    }
    const float inv = 1.0f / L;
    float* op = out + row * 128 + cg * 8;
    f32x4 lo = (f32x4){acc[0] * inv, acc[1] * inv, acc[2] * inv, acc[3] * inv};
    f32x4 hi = (f32x4){acc[4] * inv, acc[5] * inv, acc[6] * inv, acc[7] * inv};
    *(f32x4*)op = lo;
    *(f32x4*)(op + 4) = hi;
}

// ---------------------------------------------------------------------------
extern "C" void kernel_launch(void* const* d_in, const int* in_sizes, int n_in,
                              void* d_out, int out_size, void* d_ws, size_t ws_size,
                              hipStream_t stream) {
    const float* xq = (const float*)d_in[0];
    const float* xk = (const float*)d_in[1];
    const float* xv = (const float*)d_in[2];
    const float* Wq = (const float*)d_in[3];
    const float* bq = (const float*)d_in[4];
    const float* Wk = (const float*)d_in[5];
    const float* bk = (const float*)d_in[6];
    const float* Wv = (const float*)d_in[7];
    const float* bv = (const float*)d_in[8];
    float* out = (float*)d_out;

    // ws layout: wt 192K | qo 4M | ko 4M | vt 4M | ml 1M | opart SPLIT*4M
    char* ws = (char*)d_ws;
    _Float16* wt    = (_Float16*)ws;
    _Float16* qo    = (_Float16*)(ws + 196608);
    _Float16* ko    = (_Float16*)(ws + 196608 + 4194304);
    _Float16* vt    = (_Float16*)(ws + 196608 + 2 * 4194304);
    float2*   ml    = (float2*)  (ws + 196608 + 3 * 4194304);
    _Float16* opart = (_Float16*)(ws + 196608 + 3 * 4194304 + 1048576);
    _Float16* vtmp  = opart;   // alias, lifetime disjoint

    hipLaunchKernelGGL(prep_weights, dim3(24), dim3(256), 0, stream,
                       Wq, Wk, Wv, wt);
    hipLaunchKernelGGL(proj_kernel, dim3(256, 3), dim3(256), 0, stream,
                       xq, xk, xv, wt, bq, bk, bv, qo, ko, vtmp);
    hipLaunchKernelGGL(transpose_v, dim3(32, 2, 8), dim3(256), 0, stream,
                       vtmp, vt);
    hipLaunchKernelGGL(attn_kernel, dim3(16 * 8 * SPLIT), dim3(512), 0, stream,
                       qo, ko, vt, opart, ml);
    hipLaunchKernelGGL(merge_kernel, dim3(1024), dim3(256), 0, stream,
                       opart, ml, out);
}